// Round 15
// baseline (571.992 us; speedup 1.0000x reference)
//
#include <hip/hip_runtime.h>
#include <hip/hip_bf16.h>
#include <hip/hip_cooperative_groups.h>
namespace cg = cooperative_groups;

typedef unsigned short u16;
typedef unsigned int u32;
typedef __attribute__((ext_vector_type(8))) short short8;    // 8 bf16 MFMA A/B frag
typedef __attribute__((ext_vector_type(4))) float f32x4;

#define KS1 1.44269504f   // log2(e)
#define KS2 2.88539008f   // 2*log2(e)

__device__ __forceinline__ float bf2f(u16 u) {
    union { u32 i; float f; } v; v.i = ((u32)u) << 16; return v.f;
}
__device__ __forceinline__ u16 f2bf(float f) {            // RNE
    union { float f; u32 i; } v; v.f = f;
    u32 r = v.i + 0x7fffu + ((v.i >> 16) & 1u);
    return (u16)(r >> 16);
}
__device__ __forceinline__ u32 pack_bf2(float lo, float hi) {
    return __builtin_amdgcn_perm(__float_as_uint(hi), __float_as_uint(lo), 0x07060302u);
}
__device__ __forceinline__ u32 pack_relu(float a, float b) {
    return (u32)f2bf(fmaxf(a, 0.f)) | ((u32)f2bf(fmaxf(b, 0.f)) << 16);
}
__device__ __forceinline__ f32x4 bias4(const u16* b) {
    uint2 u = *(const uint2*)b;
    f32x4 r;
    r[0] = bf2f((u16)(u.x & 0xffffu)); r[1] = bf2f((u16)(u.x >> 16));
    r[2] = bf2f((u16)(u.y & 0xffffu)); r[3] = bf2f((u16)(u.y >> 16));
    return r;
}
// soft barrier: LDS-only drain + barrier (global loads stay in flight)
__device__ __forceinline__ void soft_barrier() {
    __asm__ __volatile__("s_waitcnt lgkmcnt(0)\n\ts_barrier" ::: "memory");
}
// XOR-swizzled exchange buffer (bank-free: <=2-way)
__device__ __forceinline__ void xwrite(u16* buf, int D2, int row, int quad, int jt, u32 w0, u32 w1) {
    int ch = jt * 2 + (quad >> 1);
    *(uint2*)(buf + row * D2 + ((ch ^ (row & 7)) << 3) + ((quad & 1) << 2)) = (uint2){w0, w1};
}
__device__ __forceinline__ short8 xread(const u16* buf, int D2, int row, int quad, int kc) {
    return *(const short8*)(buf + row * D2 + (((kc * 4 + quad) ^ (row & 7)) << 3));
}
#define MFMA16 __builtin_amdgcn_mfma_f32_16x16x32_bf16

#define NONLIN(ACC, CST, HW0, HW1)                                             \
    {                                                                          \
        float hv[4];                                                           \
        _Pragma("unroll") for (int r = 0; r < 4; ++r) {                        \
            float iv = ACC[0][r], fv = ACC[1][r], gv = ACC[2][r], ov = ACC[3][r]; \
            float e_i = __builtin_amdgcn_exp2f(-iv);                           \
            float e_f = __builtin_amdgcn_exp2f(-fv);                           \
            float e_g = __builtin_amdgcn_exp2f(gv);                            \
            float sf  = __builtin_amdgcn_rcpf(1.0f + e_f);                     \
            float rig = __builtin_amdgcn_rcpf((1.0f + e_i) * (1.0f + e_g));    \
            float tt  = __builtin_fmaf(e_g, KS2, -KS2);                        \
            float cn  = __builtin_fmaf(sf, CST[r], tt * rig);                  \
            CST[r] = cn;                                                       \
            float e_c = __builtin_amdgcn_exp2f(cn);                            \
            float e_o = __builtin_amdgcn_exp2f(-ov);                           \
            float roc = __builtin_amdgcn_rcpf((1.0f + e_o) * (1.0f + e_c));    \
            hv[r] = (e_c - 1.0f) * roc;                                        \
        }                                                                      \
        HW0 = pack_bf2(hv[0], hv[1]);                                          \
        HW1 = pack_bf2(hv[2], hv[3]);                                          \
    }

// stage scaled bias -> lds_b, load weight frags into registers
#define LSTM_WEIGHTS(WIHS, WHHS, BIH, BHH)                                     \
    {                                                                          \
        int j = tid;                                                           \
        float sc = (j >= 128 && j < 192) ? KS2 : KS1;                          \
        lds_b[j] = (bf2f(BIH[j]) + bf2f(BHH[j])) * sc;                         \
    }                                                                          \
    short8 wf[8], hf[8];                                                       \
    _Pragma("unroll") for (int g = 0; g < 4; ++g) {                            \
        int jt = w + 4 * g;                                                    \
        const u16* wi = (WIHS) + (size_t)(jt * 16 + col) * 64 + quad * 8;      \
        const u16* wh = (WHHS) + (size_t)(jt * 16 + col) * 64 + quad * 8;      \
        wf[g * 2 + 0] = *(const short8*)(wi);                                  \
        wf[g * 2 + 1] = *(const short8*)(wi + 32);                             \
        hf[g * 2 + 0] = *(const short8*)(wh);                                  \
        hf[g * 2 + 1] = *(const short8*)(wh + 32);                             \
    }

#define LSTM_GROUP_INIT                                                        \
    int4 sidxA = *(const int4*)(src + (size_t)nodeA * 16 + quad * 4);          \
    int4 sidxB = *(const int4*)(src + (size_t)nodeB * 16 + quad * 4);          \
    short8 xbA0, xbA1, xbB0, xbB1;                                             \
    {                                                                          \
        int sA = __shfl(sidxA.x, col, 64);                                     \
        const u16* pA = xp + (size_t)sA * 64 + quad * 8;                       \
        xbA0 = *(const short8*)pA; xbA1 = *(const short8*)(pA + 32);           \
        int sB = __shfl(sidxB.x, col, 64);                                     \
        const u16* pB = xp + (size_t)sB * 64 + quad * 8;                       \
        xbB0 = *(const short8*)pB; xbB1 = *(const short8*)(pB + 32);           \
    }

#define LSTM2_CORE_LOOP                                                        \
    short8 hbA0 = (short8){0,0,0,0,0,0,0,0};                                   \
    short8 hbA1 = hbA0, hbB0 = hbA0, hbB1 = hbA0;                              \
    float cA[4], cB[4];                                                        \
    _Pragma("unroll") for (int i = 0; i < 4; ++i) { cA[i] = 0.f; cB[i] = 0.f; }\
    soft_barrier();                                                            \
    _Pragma("unroll 1") for (int t = 0; t < 16; ++t) {                         \
        f32x4 accA[4], accB[4];                                                \
        _Pragma("unroll") for (int g = 0; g < 4; ++g) {                        \
            f32x4 bc = *(const f32x4*)(lds_b + (w + 4 * g) * 16 + quad * 4);   \
            accA[g] = MFMA16(wf[g * 2 + 0], xbA0, bc, 0, 0, 0);                \
            accB[g] = MFMA16(wf[g * 2 + 0], xbB0, bc, 0, 0, 0);                \
            accA[g] = MFMA16(wf[g * 2 + 1], xbA1, accA[g], 0, 0, 0);           \
            accB[g] = MFMA16(wf[g * 2 + 1], xbB1, accB[g], 0, 0, 0);           \
        }                                                                      \
        if (t < 15) {                                                          \
            int tn = t + 1;                                                    \
            int cvA = (tn & 2) ? ((tn & 1) ? sidxA.w : sidxA.z)                \
                               : ((tn & 1) ? sidxA.y : sidxA.x);               \
            int snA = __shfl(cvA, ((tn >> 2) << 4) + col, 64);                 \
            const u16* pA = xp + (size_t)snA * 64 + quad * 8;                  \
            xbA0 = *(const short8*)pA; xbA1 = *(const short8*)(pA + 32);       \
            int cvB = (tn & 2) ? ((tn & 1) ? sidxB.w : sidxB.z)                \
                               : ((tn & 1) ? sidxB.y : sidxB.x);               \
            int snB = __shfl(cvB, ((tn >> 2) << 4) + col, 64);                 \
            const u16* pB = xp + (size_t)snB * 64 + quad * 8;                  \
            xbB0 = *(const short8*)pB; xbB1 = *(const short8*)(pB + 32);       \
        }                                                                      \
        if (t > 0) {                                                           \
            _Pragma("unroll") for (int g = 0; g < 4; ++g) {                    \
                accA[g] = MFMA16(hf[g * 2 + 0], hbA0, accA[g], 0, 0, 0);       \
                accB[g] = MFMA16(hf[g * 2 + 0], hbB0, accB[g], 0, 0, 0);       \
                accA[g] = MFMA16(hf[g * 2 + 1], hbA1, accA[g], 0, 0, 0);       \
                accB[g] = MFMA16(hf[g * 2 + 1], hbB1, accB[g], 0, 0, 0);       \
            }                                                                  \
        }                                                                      \
        u32 hwA0, hwA1, hwB0, hwB1;                                            \
        NONLIN(accA, cA, hwA0, hwA1)                                           \
        NONLIN(accB, cB, hwB0, hwB1)                                           \
        u16* hbuf = lds_h[t & 1];                                              \
        xwrite(hbuf, 64, col,      quad, w, hwA0, hwA1);                       \
        xwrite(hbuf, 64, col + 16, quad, w, hwB0, hwB1);                       \
        soft_barrier();                                                        \
        hbA0 = xread(hbuf, 64, col,      quad, 0);                             \
        hbA1 = xread(hbuf, 64, col,      quad, 1);                             \
        hbB0 = xread(hbuf, 64, col + 16, quad, 0);                             \
        hbB1 = xread(hbuf, 64, col + 16, quad, 1);                             \
    }

// ======== shared epilogue bodies (used by fused + fallback kernels) ========
#define EPI_MID(XROOT, LLW, LLB, LRW, PW, PB, Y1P, XP2P, BUF)                  \
    {                                                                          \
        const u16* wr  = (LLW) + (size_t)(w * 16 + col) * 64 + quad * 8;       \
        short8 ll0 = *(const short8*)wr, ll1 = *(const short8*)(wr + 32);      \
        const u16* wr2 = (LRW) + (size_t)(w * 16 + col) * 64 + quad * 8;       \
        short8 lr0 = *(const short8*)wr2, lr1 = *(const short8*)(wr2 + 32);    \
        f32x4 bY = bias4((LLB) + w * 16 + quad * 4);                           \
        const u16* xrA = (XROOT) + (size_t)nodeA * 64 + quad * 8;              \
        short8 rxA0 = *(const short8*)xrA, rxA1 = *(const short8*)(xrA + 32);  \
        const u16* xrB = (XROOT) + (size_t)nodeB * 64 + quad * 8;              \
        short8 rxB0 = *(const short8*)xrB, rxB1 = *(const short8*)(xrB + 32);  \
        f32x4 aA = MFMA16(ll0, hbA0, bY, 0, 0, 0);                             \
        aA = MFMA16(ll1, hbA1, aA, 0, 0, 0);                                   \
        aA = MFMA16(lr0, rxA0, aA, 0, 0, 0);                                   \
        aA = MFMA16(lr1, rxA1, aA, 0, 0, 0);                                   \
        f32x4 aB = MFMA16(ll0, hbB0, bY, 0, 0, 0);                             \
        aB = MFMA16(ll1, hbB1, aB, 0, 0, 0);                                   \
        aB = MFMA16(lr0, rxB0, aB, 0, 0, 0);                                   \
        aB = MFMA16(lr1, rxB1, aB, 0, 0, 0);                                   \
        u32 yA0 = pack_relu(aA[0], aA[1]), yA1 = pack_relu(aA[2], aA[3]);      \
        u32 yB0 = pack_relu(aB[0], aB[1]), yB1 = pack_relu(aB[2], aB[3]);      \
        *(uint2*)((Y1P) + (size_t)nodeA * 64 + w * 16 + quad * 4) = (uint2){yA0, yA1}; \
        if (actB) *(uint2*)((Y1P) + (size_t)nodeB * 64 + w * 16 + quad * 4) = (uint2){yB0, yB1}; \
        xwrite(BUF, 64, col,      quad, w, yA0, yA1);                          \
        xwrite(BUF, 64, col + 16, quad, w, yB0, yB1);                          \
        soft_barrier();                                                        \
        const u16* wp = (PW) + (size_t)(w * 16 + col) * 64 + quad * 8;         \
        short8 p0 = *(const short8*)wp, p1 = *(const short8*)(wp + 32);        \
        f32x4 bp = bias4((PB) + w * 16 + quad * 4);                            \
        short8 ybA0 = xread(BUF, 64, col,      quad, 0);                       \
        short8 ybA1 = xread(BUF, 64, col,      quad, 1);                       \
        short8 ybB0 = xread(BUF, 64, col + 16, quad, 0);                       \
        short8 ybB1 = xread(BUF, 64, col + 16, quad, 1);                       \
        f32x4 a2A = MFMA16(p0, ybA0, bp, 0, 0, 0);                             \
        a2A = MFMA16(p1, ybA1, a2A, 0, 0, 0);                                  \
        f32x4 a2B = MFMA16(p0, ybB0, bp, 0, 0, 0);                             \
        a2B = MFMA16(p1, ybB1, a2B, 0, 0, 0);                                  \
        *(uint2*)((XP2P) + (size_t)nodeA * 64 + w * 16 + quad * 4) =           \
            (uint2){pack_relu(a2A[0], a2A[1]), pack_relu(a2A[2], a2A[3])};     \
        if (actB) *(uint2*)((XP2P) + (size_t)nodeB * 64 + w * 16 + quad * 4) = \
            (uint2){pack_relu(a2B[0], a2B[1]), pack_relu(a2B[2], a2B[3])};     \
        soft_barrier();                                                        \
    }

#define EPI_POST(Y1P, LLW2, LLB2, LRW2, W1M, B1M, W2M, B2M, W3M, B3M, OUTP, BUFA, BUFB) \
    {                                                                          \
        const u16* yrA = (Y1P) + (size_t)nodeA * 64 + quad * 8;                \
        short8 ryA0 = *(const short8*)yrA, ryA1 = *(const short8*)(yrA + 32);  \
        const u16* yrB = (Y1P) + (size_t)nodeB * 64 + quad * 8;                \
        short8 ryB0 = *(const short8*)yrB, ryB1 = *(const short8*)(yrB + 32);  \
        _Pragma("unroll") for (int ti = 0; ti < 2; ++ti) {                     \
            int jt = 2 * w + ti;                                               \
            const u16* wr = (LLW2) + (size_t)(jt * 16 + col) * 64 + quad * 8;  \
            short8 l0 = *(const short8*)wr, l1 = *(const short8*)(wr + 32);    \
            const u16* wr2 = (LRW2) + (size_t)(jt * 16 + col) * 64 + quad * 8; \
            short8 r0 = *(const short8*)wr2, r1 = *(const short8*)(wr2 + 32);  \
            f32x4 b0 = bias4((LLB2) + jt * 16 + quad * 4);                     \
            f32x4 aA = MFMA16(l0, hbA0, b0, 0, 0, 0);                          \
            aA = MFMA16(l1, hbA1, aA, 0, 0, 0);                                \
            aA = MFMA16(r0, ryA0, aA, 0, 0, 0);                                \
            aA = MFMA16(r1, ryA1, aA, 0, 0, 0);                                \
            xwrite(BUFA, 128, col, quad, jt, pack_relu(aA[0], aA[1]), pack_relu(aA[2], aA[3])); \
            f32x4 aB = MFMA16(l0, hbB0, b0, 0, 0, 0);                          \
            aB = MFMA16(l1, hbB1, aB, 0, 0, 0);                                \
            aB = MFMA16(r0, ryB0, aB, 0, 0, 0);                                \
            aB = MFMA16(r1, ryB1, aB, 0, 0, 0);                                \
            xwrite(BUFA, 128, col + 16, quad, jt, pack_relu(aB[0], aB[1]), pack_relu(aB[2], aB[3])); \
        }                                                                      \
        soft_barrier();                                                        \
        short8 y2A[4], y2B[4];                                                 \
        _Pragma("unroll") for (int kc = 0; kc < 4; ++kc) {                     \
            y2A[kc] = xread(BUFA, 128, col,      quad, kc);                    \
            y2B[kc] = xread(BUFA, 128, col + 16, quad, kc);                    \
        }                                                                      \
        _Pragma("unroll") for (int ti = 0; ti < 3; ++ti) {                     \
            int jt = 3 * w + ti;                                               \
            const u16* wr = (W1M) + (size_t)(jt * 16 + col) * 128 + quad * 8;  \
            short8 wk[4];                                                      \
            _Pragma("unroll") for (int kc = 0; kc < 4; ++kc) wk[kc] = *(const short8*)(wr + kc * 32); \
            f32x4 b1v = bias4((B1M) + jt * 16 + quad * 4);                     \
            f32x4 aA = b1v, aB = b1v;                                          \
            _Pragma("unroll") for (int kc = 0; kc < 4; ++kc) {                 \
                aA = MFMA16(wk[kc], y2A[kc], aA, 0, 0, 0);                     \
                aB = MFMA16(wk[kc], y2B[kc], aB, 0, 0, 0);                     \
            }                                                                  \
            xwrite(BUFB, 192, col,      quad, jt, pack_relu(aA[0], aA[1]), pack_relu(aA[2], aA[3])); \
            xwrite(BUFB, 192, col + 16, quad, jt, pack_relu(aB[0], aB[1]), pack_relu(aB[2], aB[3])); \
        }                                                                      \
        soft_barrier();                                                        \
        short8 t1A[6], t1B[6];                                                 \
        _Pragma("unroll") for (int kc = 0; kc < 6; ++kc) {                     \
            t1A[kc] = xread(BUFB, 192, col,      quad, kc);                    \
            t1B[kc] = xread(BUFB, 192, col + 16, quad, kc);                    \
        }                                                                      \
        {                                                                      \
            const u16* wr = (W2M) + (size_t)(w * 16 + col) * 192 + quad * 8;   \
            f32x4 b2v = bias4((B2M) + w * 16 + quad * 4);                      \
            f32x4 aA = b2v, aB = b2v;                                          \
            _Pragma("unroll") for (int kc = 0; kc < 6; ++kc) {                 \
                short8 wk = *(const short8*)(wr + kc * 32);                    \
                aA = MFMA16(wk, t1A[kc], aA, 0, 0, 0);                         \
                aB = MFMA16(wk, t1B[kc], aB, 0, 0, 0);                         \
            }                                                                  \
            xwrite(BUFA, 64, col,      quad, w, pack_relu(aA[0], aA[1]), pack_relu(aA[2], aA[3])); \
            xwrite(BUFA, 64, col + 16, quad, w, pack_relu(aB[0], aB[1]), pack_relu(aB[2], aB[3])); \
        }                                                                      \
        soft_barrier();                                                        \
        short8 t2A0 = xread(BUFA, 64, col,      quad, 0);                      \
        short8 t2A1 = xread(BUFA, 64, col,      quad, 1);                      \
        short8 t2B0 = xread(BUFA, 64, col + 16, quad, 0);                      \
        short8 t2B1 = xread(BUFA, 64, col + 16, quad, 1);                      \
        {                                                                      \
            const u16* wr = (W3M) + (size_t)(w * 16 + col) * 64 + quad * 8;    \
            short8 l0 = *(const short8*)wr, l1 = *(const short8*)(wr + 32);    \
            f32x4 b3v = bias4((B3M) + w * 16 + quad * 4);                      \
            f32x4 aA = MFMA16(l0, t2A0, b3v, 0, 0, 0);                         \
            aA = MFMA16(l1, t2A1, aA, 0, 0, 0);                                \
            f32x4 aB = MFMA16(l0, t2B0, b3v, 0, 0, 0);                         \
            aB = MFMA16(l1, t2B1, aB, 0, 0, 0);                                \
            float4 oA;                                                         \
            oA.x = fmaxf(aA[0], 0.f); oA.y = fmaxf(aA[1], 0.f);                \
            oA.z = fmaxf(aA[2], 0.f); oA.w = fmaxf(aA[3], 0.f);                \
            *(float4*)((OUTP) + (size_t)nodeA * 64 + w * 16 + quad * 4) = oA;  \
            if (actB) {                                                        \
                float4 oB;                                                     \
                oB.x = fmaxf(aB[0], 0.f); oB.y = fmaxf(aB[1], 0.f);            \
                oB.z = fmaxf(aB[2], 0.f); oB.w = fmaxf(aB[3], 0.f);            \
                *(float4*)((OUTP) + (size_t)nodeB * 64 + w * 16 + quad * 4) = oB; \
            }                                                                  \
        }                                                                      \
        soft_barrier();                                                        \
    }

#define PRE_BODY(STRIDE)                                                       \
    {                                                                          \
        const int wave = w;                                                    \
        _Pragma("unroll 1")                                                    \
        for (int tile = bid; tile < ntiles; tile += (STRIDE)) {                \
            const int row0 = tile * 64 + wave * 16;                            \
            if (row0 >= N) continue;                                           \
            f32x4 c1[4];                                                       \
            _Pragma("unroll") for (int jt = 0; jt < 4; ++jt) c1[jt] = (f32x4){0.f, 0.f, 0.f, 0.f}; \
            {                                                                  \
                const u16* xrow = Xin + (size_t)(row0 + col) * 64 + quad * 8;  \
                const u16* wrow = pwp + (size_t)col * 64 + quad * 8;           \
                _Pragma("unroll") for (int kc = 0; kc < 64; kc += 32) {        \
                    short8 a = *(const short8*)(xrow + kc);                    \
                    _Pragma("unroll") for (int jt = 0; jt < 4; ++jt) {         \
                        short8 b = *(const short8*)(wrow + (size_t)jt * 16 * 64 + kc); \
                        c1[jt] = MFMA16(a, b, c1[jt], 0, 0, 0);                \
                    }                                                          \
                }                                                              \
            }                                                                  \
            _Pragma("unroll") for (int jt = 0; jt < 4; ++jt) {                 \
                float bias = bf2f(pbp[jt * 16 + col]);                         \
                _Pragma("unroll") for (int r = 0; r < 4; ++r) {                \
                    float v = fmaxf(c1[jt][r] + bias, 0.f);                    \
                    xp1p[(size_t)(row0 + quad * 4 + r) * 64 + jt * 16 + col] = f2bf(v); \
                }                                                              \
            }                                                                  \
        }                                                                      \
        for (int i = bid * 256 + tid; i < n4; i += (STRIDE) * 256) {           \
            int4 v = *(const int4*)(edgep + (size_t)i * 4);                    \
            float4 o;                                                          \
            o.x = (float)v.x; o.y = (float)v.y; o.z = (float)v.z; o.w = (float)v.w; \
            *(float4*)(eoutp + (size_t)i * 4) = o;                             \
        }                                                                      \
        if (bid < 4) {                                                         \
            const u16* Wsrc = (bid == 0) ? w1i : (bid == 1) ? w1h : (bid == 2) ? w2i : w2h; \
            u16* Wdst = wssp + (size_t)bid * 16384;                            \
            for (int idx = tid; idx < 16384; idx += 256) {                     \
                int row = idx >> 6;                                            \
                float sc = (row >= 128 && row < 192) ? KS2 : KS1;              \
                Wdst[idx] = f2bf(bf2f(Wsrc[idx]) * sc);                        \
            }                                                                  \
        }                                                                      \
    }

struct Params {
    const u16* x; const int* edge;
    const u16 *p1_pw, *p1_pb, *p1_wih, *p1_whh, *p1_bih, *p1_bhh, *p1_llw, *p1_llb, *p1_lrw;
    const u16 *p2_pw, *p2_pb, *p2_wih, *p2_whh, *p2_bih, *p2_bhh, *p2_llw, *p2_llb, *p2_lrw;
    const u16 *lin1w, *lin1b, *lin2w, *lin2b, *lin3w, *lin3b;
    u16 *wss, *xp1, *xp2, *y1;
    float *out_h, *out_edge;
    int N, n4;
};

// ===========================================================================
// Cooperative fused kernel: phase0 -> grid sync -> phase1 -> grid sync -> phase2
// ===========================================================================
__global__ __launch_bounds__(256) void fused_kernel(Params pa)
{
    __shared__ float lds_b[256];
    __shared__ u16 lds_h[2][32 * 64];
    __shared__ u16 bufA[32 * 128];
    __shared__ u16 bufB[32 * 192];

    const int bid  = blockIdx.x;
    const int gsz  = gridDim.x;
    const int tid  = threadIdx.x;
    const int lane = tid & 63;
    const int w    = tid >> 6;
    const int col  = lane & 15;
    const int quad = lane >> 4;
    const int N    = pa.N;
    const int ngroups = (N + 31) / 32;
    const int ntiles  = (N + 63) / 64;
    const int n4 = pa.n4;

    // phase 0
    {
        const u16* Xin  = pa.x;
        const u16* pwp  = pa.p1_pw;
        const u16* pbp  = pa.p1_pb;
        u16* xp1p = pa.xp1;
        const int* edgep = pa.edge;
        float* eoutp = pa.out_edge;
        const u16 *w1i = pa.p1_wih, *w1h = pa.p1_whh, *w2i = pa.p2_wih, *w2h = pa.p2_whh;
        u16* wssp = pa.wss;
        PRE_BODY(gsz)
    }
    __threadfence();
    cg::this_grid().sync();
    __threadfence();

    // phase 1: layer-1 LSTM + Y1 + xp2
    {
        const u16* xp  = pa.xp1;
        const int* src = pa.edge;
        LSTM_WEIGHTS(pa.wss, pa.wss + 16384, pa.p1_bih, pa.p1_bhh)
#pragma unroll 1
        for (int grp = bid; grp < ngroups; grp += gsz) {
            const int node0 = grp * 32;
            const bool actB = (node0 + 32 <= N);
            const int nodeA = node0 + col;
            const int nodeB = actB ? (node0 + 16 + col) : nodeA;
            LSTM_GROUP_INIT
            LSTM2_CORE_LOOP
            EPI_MID(pa.x, pa.p1_llw, pa.p1_llb, pa.p1_lrw, pa.p2_pw, pa.p2_pb, pa.y1, pa.xp2, bufA)
        }
    }
    __threadfence();
    cg::this_grid().sync();
    __threadfence();

    // phase 2: layer-2 LSTM + MLP head
    {
        const u16* xp  = pa.xp2;
        const int* src = pa.edge;
        LSTM_WEIGHTS(pa.wss + 32768, pa.wss + 49152, pa.p2_bih, pa.p2_bhh)
#pragma unroll 1
        for (int grp = bid; grp < ngroups; grp += gsz) {
            const int node0 = grp * 32;
            const bool actB = (node0 + 32 <= N);
            const int nodeA = node0 + col;
            const int nodeB = actB ? (node0 + 16 + col) : nodeA;
            LSTM_GROUP_INIT
            LSTM2_CORE_LOOP
            EPI_POST(pa.y1, pa.p2_llw, pa.p2_llb, pa.p2_lrw, pa.lin1w, pa.lin1b,
                     pa.lin2w, pa.lin2b, pa.lin3w, pa.lin3b, pa.out_h, bufA, bufB)
        }
    }
}

// ===========================================================================
// Fallback path (round-13 structure, known-good 357us)
// ===========================================================================
__global__ __launch_bounds__(256) void k_pre(Params pa)
{
    const int bid  = blockIdx.x;
    const int tid  = threadIdx.x;
    const int lane = tid & 63;
    const int w    = tid >> 6;
    const int col  = lane & 15;
    const int quad = lane >> 4;
    const int N    = pa.N;
    const int ntiles = (N + 63) / 64;
    const int n4 = pa.n4;
    const u16* Xin  = pa.x;
    const u16* pwp  = pa.p1_pw;
    const u16* pbp  = pa.p1_pb;
    u16* xp1p = pa.xp1;
    const int* edgep = pa.edge;
    float* eoutp = pa.out_edge;
    const u16 *w1i = pa.p1_wih, *w1h = pa.p1_whh, *w2i = pa.p2_wih, *w2h = pa.p2_whh;
    u16* wssp = pa.wss;
    PRE_BODY((int)gridDim.x)
}

__global__ __launch_bounds__(256) void lstm_mid_k(Params pa)
{
    __shared__ float lds_b[256];
    __shared__ u16 lds_h[2][32 * 64];
    __shared__ u16 bufA[32 * 128];

    const int tid  = threadIdx.x;
    const int lane = tid & 63;
    const int w    = tid >> 6;
    const int col  = lane & 15;
    const int quad = lane >> 4;
    const int N    = pa.N;
    const u16* xp  = pa.xp1;
    const int* src = pa.edge;
    LSTM_WEIGHTS(pa.wss, pa.wss + 16384, pa.p1_bih, pa.p1_bhh)

#pragma unroll 1
    for (int rep = 0; rep < 2; ++rep) {
        const int node0 = (blockIdx.x * 2 + rep) * 32;
        if (node0 >= N) break;
        const bool actB = (node0 + 32 <= N);
        const int nodeA = node0 + col;
        const int nodeB = actB ? (node0 + 16 + col) : nodeA;
        LSTM_GROUP_INIT
        LSTM2_CORE_LOOP
        EPI_MID(pa.x, pa.p1_llw, pa.p1_llb, pa.p1_lrw, pa.p2_pw, pa.p2_pb, pa.y1, pa.xp2, bufA)
    }
}

__global__ __launch_bounds__(256) void lstm_post_k(Params pa)
{
    __shared__ float lds_b[256];
    __shared__ u16 lds_h[2][32 * 64];
    __shared__ u16 bufA[32 * 128];
    __shared__ u16 bufB[32 * 192];

    const int tid  = threadIdx.x;
    const int lane = tid & 63;
    const int w    = tid >> 6;
    const int col  = lane & 15;
    const int quad = lane >> 4;
    const int N    = pa.N;
    const u16* xp  = pa.xp2;
    const int* src = pa.edge;
    LSTM_WEIGHTS(pa.wss + 32768, pa.wss + 49152, pa.p2_bih, pa.p2_bhh)

#pragma unroll 1
    for (int rep = 0; rep < 2; ++rep) {
        const int node0 = (blockIdx.x * 2 + rep) * 32;
        if (node0 >= N) break;
        const bool actB = (node0 + 32 <= N);
        const int nodeA = node0 + col;
        const int nodeB = actB ? (node0 + 16 + col) : nodeA;
        LSTM_GROUP_INIT
        LSTM2_CORE_LOOP
        EPI_POST(pa.y1, pa.p2_llw, pa.p2_llb, pa.p2_lrw, pa.lin1w, pa.lin1b,
                 pa.lin2w, pa.lin2b, pa.lin3w, pa.lin3b, pa.out_h, bufA, bufB)
    }
}

// ---------------------------------------------------------------------------
extern "C" void kernel_launch(void* const* d_in, const int* in_sizes, int n_in,
                              void* d_out, int out_size, void* d_ws, size_t ws_size,
                              hipStream_t stream)
{
    Params pa;
    pa.x      = (const u16*)d_in[0];
    pa.edge   = (const int*)d_in[1];
    pa.p1_pw  = (const u16*)d_in[3];  pa.p1_pb  = (const u16*)d_in[4];
    pa.p1_wih = (const u16*)d_in[5];  pa.p1_whh = (const u16*)d_in[6];
    pa.p1_bih = (const u16*)d_in[7];  pa.p1_bhh = (const u16*)d_in[8];
    pa.p1_llw = (const u16*)d_in[9];  pa.p1_llb = (const u16*)d_in[10];
    pa.p1_lrw = (const u16*)d_in[11];
    pa.p2_pw  = (const u16*)d_in[12]; pa.p2_pb  = (const u16*)d_in[13];
    pa.p2_wih = (const u16*)d_in[14]; pa.p2_whh = (const u16*)d_in[15];
    pa.p2_bih = (const u16*)d_in[16]; pa.p2_bhh = (const u16*)d_in[17];
    pa.p2_llw = (const u16*)d_in[18]; pa.p2_llb = (const u16*)d_in[19];
    pa.p2_lrw = (const u16*)d_in[20];
    pa.lin1w  = (const u16*)d_in[21]; pa.lin1b  = (const u16*)d_in[22];
    pa.lin2w  = (const u16*)d_in[23]; pa.lin2b  = (const u16*)d_in[24];
    pa.lin3w  = (const u16*)d_in[25]; pa.lin3b  = (const u16*)d_in[26];
    (void)n_in; (void)ws_size; (void)out_size;

    const int N  = in_sizes[0] / 64;     // 50000
    const int E2 = in_sizes[1];          // 1600000

    char* w = (char*)d_ws;
    pa.wss = (u16*)(w);                          // 128KB scaled weights
    pa.xp1 = (u16*)(w + 1u  * 1024 * 1024);
    pa.xp2 = (u16*)(w + 8u  * 1024 * 1024);
    pa.y1  = (u16*)(w + 15u * 1024 * 1024);
    pa.out_h    = (float*)d_out;
    pa.out_edge = (float*)d_out + (size_t)N * 64;
    pa.N  = N;
    pa.n4 = E2 / 4;

    // cooperative grid size from the runtime's own occupancy math (the r14
    // launch was rejected silently; don't guess the residency).
    int occ = 0;
    hipError_t qerr = hipOccupancyMaxActiveBlocksPerMultiprocessor(
        &occ, (const void*)fused_kernel, 256, 0);
    int grid = (qerr == hipSuccess && occ > 0) ? occ * 256 : 0;
    if (grid > 512) grid = 512;

    hipError_t lerr = hipErrorUnknown;
    if (grid > 0) {
        void* kargs[] = { (void*)&pa };
        lerr = hipLaunchCooperativeKernel((const void*)fused_kernel, dim3(grid),
                                          dim3(256), kargs, 0, stream);
    }
    if (lerr != hipSuccess) {
        // fallback: round-13 three-dispatch path (known-good)
        const int tiles = (N + 63) / 64;
        const int gpre  = (tiles + 1) / 2;
        const int gbl   = (N + 63) / 64;
        hipLaunchKernelGGL(k_pre,       dim3(gpre), dim3(256), 0, stream, pa);
        hipLaunchKernelGGL(lstm_mid_k,  dim3(gbl),  dim3(256), 0, stream, pa);
        hipLaunchKernelGGL(lstm_post_k, dim3(gbl),  dim3(256), 0, stream, pa);
    }
}